// Round 4
// baseline (591.038 us; speedup 1.0000x reference)
//
#include <hip/hip_runtime.h>
#include <math.h>

// PointLoss R3: two-phase restructure.
// Phase 1 (streaming, no gathers): fov terms + wave-compacted queue of
//   (p, gather_index) for pixels passing mask0 & inb & conf>=0.5 (~5.5%).
// Phase 2 (gathers only): processes the queue with full MLP (no transcendental
//   -> gather dependence anywhere).
// Fast atan2/asin (minimax / Taylor-core): |err| < 5e-5 rad, vs tolerance
//   73.9 on a ~3700-magnitude output (error contribution ~O(0.1)).

namespace {
constexpr int B_ = 64, H_ = 52, W_ = 720;
constexpr int HW_ = H_ * W_;            // 37440
constexpr int NPIX = B_ * HW_;          // 2396160
constexpr int NT = 256;
constexpr int NB1 = 2048;               // 8192 waves = exactly 1.0 residency
constexpr int STRIDE = NB1 * NT;        // 524288
constexpr int NITER = (NPIX + STRIDE - 1) / STRIDE;  // 5
constexpr int NB2 = 256;                // phase-2 grid
constexpr float EPSF = 1e-8f;
constexpr float RAD2DEG = 57.29577951308232f;
// d_ws layout
constexpr size_t OFF_CNT = 0;                                   // uint32
constexpr size_t OFF_P1  = 256;                                 // NB1*2 floats
constexpr size_t OFF_P2  = OFF_P1 + (size_t)NB1 * 2 * 4;        // NB2*3 floats
constexpr size_t OFF_Q   = 65536;                               // int2 queue
}

__device__ __forceinline__ float atan_poly01(float z) {  // atan(z), z in [0,1]
    const float z2 = z * z;
    float r = fmaf(z2, -0.0117212f, 0.0526526f);
    r = fmaf(z2, r, -0.1164329f);
    r = fmaf(z2, r,  0.1935435f);
    r = fmaf(z2, r, -0.3326235f);
    r = fmaf(z2, r,  0.9999773f);
    return r * z;
}

__device__ __forceinline__ float atan2_fast(float y, float x) {
    const float ax = fabsf(x), ay = fabsf(y);
    const float mx = fmaxf(ax, ay), mn = fminf(ax, ay);
    const float z = mn * __builtin_amdgcn_rcpf(fmaxf(mx, 1e-37f));
    float a = atan_poly01(z);
    if (ay > ax) a = 1.5707964f - a;
    if (x < 0.0f) a = 3.1415927f - a;
    return copysignf(a, y);
}

__device__ __forceinline__ float asin_core(float x) {  // asin(x), x in [0,0.5]
    const float x2 = x * x;
    float r = fmaf(x2, 0.03038196f, 0.04464286f);
    r = fmaf(x2, r, 0.075f);
    r = fmaf(x2, r, 0.16666667f);
    return fmaf(x * x2, r, x);
}

__device__ __forceinline__ float asin_fast(float q) {  // q in [-1,1]
    const float a = fabsf(q);
    const float r1 = asin_core(a);
    const float s = sqrtf(fmaxf(0.5f * (1.0f - a), 0.0f));
    const float r2 = 1.5707964f - 2.0f * asin_core(s);
    const float r = (a > 0.5f) ? r2 : r1;
    return copysignf(r, q);
}

__global__ __launch_bounds__(NT) void pl_phase1(
    const float* __restrict__ v,      // vertexmap_proj [B,H,W,3]
    const float* __restrict__ nown,   // now_normalmap  [B,H,W,3]
    const float* __restrict__ conf,   // now_confidencemap
    const int*   __restrict__ nowm,   // now_maskmap
    unsigned int* __restrict__ counter,
    int2* __restrict__ queue, unsigned int cap,
    float* __restrict__ p1)           // [NB1*2] : m0count, fovsum
{
    float s_m0 = 0.f, s_fov = 0.f;
    const int lane = threadIdx.x & 63;
    int p = blockIdx.x * NT + threadIdx.x;   // < NPIX for iter 0

    float vx = v[3*p], vy = v[3*p+1], vz = v[3*p+2];
    float ax = nown[3*p], ay = nown[3*p+1], az = nown[3*p+2];
    int   mi = nowm[p];
    float cf = conf[p];

    #pragma unroll
    for (int it = 0; it < NITER; ++it) {
        // prefetch next iteration's streaming data
        const int pn = p + STRIDE;
        const bool hasnext = (it + 1 < NITER) && (pn < NPIX);
        const int pl = hasnext ? pn : p;
        const float nvx = v[3*pl], nvy = v[3*pl+1], nvz = v[3*pl+2];
        const float nax = nown[3*pl], nay = nown[3*pl+1], naz = nown[3*pl+2];
        const int   nmi = nowm[pl];
        const float ncf = conf[pl];

        const bool valid = (p < NPIX);
        const bool mask0 = valid && (mi > 0) &&
                           ((fabsf(ax) + fabsf(ay) + fabsf(az)) != 0.0f);

        const float d2 = vx*vx + vy*vy + vz*vz + EPSF;
        const float q  = fminf(fmaxf(vz * __builtin_amdgcn_rsqf(d2), -1.f), 1.f);
        const float yaw   = atan2_fast(vy, vx) * RAD2DEG;
        const float pitch = asin_fast(q) * RAD2DEG;
        const float px = (180.0f - yaw) * 2.0f;
        const float py = (3.0f - pitch) * 2.0f;

        if (mask0) {
            const float dx = px - fminf(fmaxf(px, 0.f), 719.0f);
            const float dy = py - fminf(fmaxf(py, 0.f), 51.0f);
            s_m0 += 1.0f;
            s_fov += dx*dx + dy*dy;
        }

        const float prx = rintf(px), pry = rintf(py);   // round-half-even
        const bool inb = (prx >= 0.f) && (prx < 720.f) &&
                         (pry >= 0.f) && (pry < 52.f);
        const bool pred = mask0 && inb && (cf >= 0.5f);

        // wave-compacted enqueue: one atomic per wave
        const unsigned long long bal = __ballot(pred);
        if (bal) {
            unsigned int base = 0;
            if (lane == 0) base = atomicAdd(counter, (unsigned)__popcll(bal));
            base = (unsigned)__shfl((int)base, 0);
            if (pred) {
                const unsigned int idx =
                    base + (unsigned)__popcll(bal & ((1ull << lane) - 1ull));
                if (idx < cap) {
                    const int gi = (p / HW_) * HW_ + (int)pry * W_ + (int)prx;
                    queue[idx] = make_int2(p, gi);
                }
            }
        }

        vx = nvx; vy = nvy; vz = nvz;
        ax = nax; ay = nay; az = naz;
        mi = nmi; cf = ncf; p = pn;
    }

    #pragma unroll
    for (int off = 32; off > 0; off >>= 1) {
        s_m0  += __shfl_down(s_m0,  off);
        s_fov += __shfl_down(s_fov, off);
    }
    __shared__ float red[NT / 64][2];
    const int wv = threadIdx.x >> 6;
    if (lane == 0) { red[wv][0] = s_m0; red[wv][1] = s_fov; }
    __syncthreads();
    if (threadIdx.x == 0) {
        float a = 0.f, b = 0.f;
        for (int w2 = 0; w2 < NT / 64; ++w2) { a += red[w2][0]; b += red[w2][1]; }
        p1[blockIdx.x * 2 + 0] = a;
        p1[blockIdx.x * 2 + 1] = b;
    }
}

__global__ __launch_bounds__(NT) void pl_phase2(
    const float* __restrict__ v,
    const float* __restrict__ nrm,
    const float* __restrict__ unc,
    const float* __restrict__ lastn,
    const float* __restrict__ lastv,
    const int*   __restrict__ lastm,
    const unsigned int* __restrict__ counter,
    const int2* __restrict__ queue, unsigned int cap,
    float* __restrict__ p2)           // [NB2*3] : mcount, icpsum, angsum
{
    float s_m = 0.f, s_icp = 0.f, s_ang = 0.f;
    unsigned int count = *counter;
    if (count > cap) count = cap;
    const unsigned int gsz = NB2 * NT;
    for (unsigned int i = blockIdx.x * NT + threadIdx.x; i < count; i += gsz) {
        const int2 rec = queue[i];
        const int p = rec.x, gi = rec.y;
        // all loads independent -> full MLP
        const float lx = lastn[3*gi], ly = lastn[3*gi+1], lz = lastn[3*gi+2];
        const int   lmv = lastm[gi];
        const float wx = lastv[3*gi], wy = lastv[3*gi+1], wz = lastv[3*gi+2];
        const float nx = nrm[3*p],  ny = nrm[3*p+1],  nz = nrm[3*p+2];
        const float u  = unc[p];
        const float vx = v[3*p], vy = v[3*p+1], vz = v[3*p+2];
        if ((lmv > 0) && ((fabsf(lx) + fabsf(ly) + fabsf(lz)) != 0.f)) {
            const float r  = lx*(vx-wx) + ly*(vy-wy) + lz*(vz-wz);
            const float dt = lx*nx + ly*ny + lz*nz;
            const float den = (lx*lx + ly*ly + lz*lz) *
                              (nx*nx + ny*ny + nz*nz) + EPSF;
            const float cosang = fabsf(dt) * __builtin_amdgcn_rsqf(den);
            s_m   += 1.0f;
            s_icp += u * fabsf(r);
            s_ang += u * (1.0f - cosang);
        }
    }

    #pragma unroll
    for (int off = 32; off > 0; off >>= 1) {
        s_m   += __shfl_down(s_m,   off);
        s_icp += __shfl_down(s_icp, off);
        s_ang += __shfl_down(s_ang, off);
    }
    __shared__ float red[NT / 64][3];
    const int lane = threadIdx.x & 63;
    const int wv = threadIdx.x >> 6;
    if (lane == 0) { red[wv][0] = s_m; red[wv][1] = s_icp; red[wv][2] = s_ang; }
    __syncthreads();
    if (threadIdx.x == 0) {
        float a = 0.f, b = 0.f, c = 0.f;
        for (int w2 = 0; w2 < NT / 64; ++w2) {
            a += red[w2][0]; b += red[w2][1]; c += red[w2][2];
        }
        p2[blockIdx.x * 3 + 0] = a;
        p2[blockIdx.x * 3 + 1] = b;
        p2[blockIdx.x * 3 + 2] = c;
    }
}

__global__ __launch_bounds__(NT) void pl_finalize(
    const float* __restrict__ p1,     // [NB1*2]
    const float* __restrict__ p2,     // [NB2*3]
    const float* __restrict__ sx,
    const float* __restrict__ sq,
    float* __restrict__ out)
{
    double m0 = 0, fov = 0, m = 0, icp = 0, ang = 0;
    for (int i = threadIdx.x; i < NB1; i += NT) {
        m0  += (double)p1[i*2+0];
        fov += (double)p1[i*2+1];
    }
    if (threadIdx.x < NB2) {
        m   += (double)p2[threadIdx.x*3+0];
        icp += (double)p2[threadIdx.x*3+1];
        ang += (double)p2[threadIdx.x*3+2];
    }
    #pragma unroll
    for (int off = 32; off > 0; off >>= 1) {
        m0  += __shfl_down(m0,  off);
        fov += __shfl_down(fov, off);
        m   += __shfl_down(m,   off);
        icp += __shfl_down(icp, off);
        ang += __shfl_down(ang, off);
    }
    __shared__ double red[NT / 64][5];
    const int lane = threadIdx.x & 63;
    const int wv = threadIdx.x >> 6;
    if (lane == 0) {
        red[wv][0] = m0; red[wv][1] = fov; red[wv][2] = m;
        red[wv][3] = icp; red[wv][4] = ang;
    }
    __syncthreads();
    if (threadIdx.x == 0) {
        double t[5] = {0, 0, 0, 0, 0};
        for (int w2 = 0; w2 < NT / 64; ++w2)
            for (int c = 0; c < 5; ++c) t[c] += red[w2][c];
        const double n0 = fmax(t[0], 1.0);
        const double n  = fmax(t[2], 1.0);
        const double sx0 = (double)sx[0], sq0 = (double)sq[0];
        const double total = exp(-sx0) * (t[3] / n) + sx0
                           + exp(-sq0) * (t[4] / n) + sq0
                           + t[1] / n0;   // LAMDA = 1, ANGRATE = 1
        out[0] = (float)total;
    }
}

extern "C" void kernel_launch(void* const* d_in, const int* in_sizes, int n_in,
                              void* d_out, int out_size, void* d_ws, size_t ws_size,
                              hipStream_t stream) {
    const float* v     = (const float*)d_in[0];
    const float* nrm   = (const float*)d_in[1];
    const float* unc   = (const float*)d_in[2];
    const float* nown  = (const float*)d_in[3];
    const float* conf  = (const float*)d_in[4];
    const float* lastn = (const float*)d_in[5];
    const float* lastv = (const float*)d_in[6];
    const float* sx    = (const float*)d_in[7];
    const float* sq    = (const float*)d_in[8];
    const int*   nowm  = (const int*)d_in[9];
    const int*   lastm = (const int*)d_in[10];

    char* ws = (char*)d_ws;
    unsigned int* counter = (unsigned int*)(ws + OFF_CNT);
    float* p1 = (float*)(ws + OFF_P1);
    float* p2 = (float*)(ws + OFF_P2);
    int2*  queue = (int2*)(ws + OFF_Q);
    size_t qcap = (ws_size > OFF_Q + sizeof(int2))
                      ? (ws_size - OFF_Q) / sizeof(int2) : 0;
    if (qcap > (size_t)NPIX) qcap = NPIX;
    const unsigned int cap = (unsigned int)qcap;

    hipMemsetAsync(counter, 0, sizeof(unsigned int), stream);
    pl_phase1<<<NB1, NT, 0, stream>>>(v, nown, conf, nowm, counter, queue, cap, p1);
    pl_phase2<<<NB2, NT, 0, stream>>>(v, nrm, unc, lastn, lastv, lastm,
                                      counter, queue, cap, p2);
    pl_finalize<<<1, NT, 0, stream>>>(p1, p2, sx, sq, (float*)d_out);
}

// Round 5
// 196.422 us; speedup vs baseline: 3.0090x; 3.0090x over previous
//
#include <hip/hip_runtime.h>
#include <math.h>

// PointLoss R4: single fused kernel, manually flattened 5-iteration software
// pipeline. __launch_bounds__(256,4) gives a ~128-VGPR budget so the compiler
// can keep all streaming + gather loads in flight (R0-R3 collapsed to 20-28
// VGPRs and serialized every load). Fast atan2/asin (validated in R3,
// absmax 0.0). 2048 blocks x 16 waves/CU = exactly 2.0 residency rounds.

namespace {
constexpr int B_ = 64, H_ = 52, W_ = 720;
constexpr int HW_ = H_ * W_;            // 37440
constexpr int NPIX = B_ * HW_;          // 2396160
constexpr int NT = 256;
constexpr int NB = 2048;
constexpr int STRIDE = NB * NT;         // 524288
constexpr int NI = 5;                   // 4 full iters + 1 partial
constexpr float EPSF = 1e-8f;
constexpr float RAD2DEG = 57.29577951308232f;
}

__device__ __forceinline__ float atan_poly01(float z) {  // atan(z), z in [0,1]
    const float z2 = z * z;
    float r = fmaf(z2, -0.0117212f, 0.0526526f);
    r = fmaf(z2, r, -0.1164329f);
    r = fmaf(z2, r,  0.1935435f);
    r = fmaf(z2, r, -0.3326235f);
    r = fmaf(z2, r,  0.9999773f);
    return r * z;
}

__device__ __forceinline__ float atan2_fast(float y, float x) {
    const float ax = fabsf(x), ay = fabsf(y);
    const float mx = fmaxf(ax, ay), mn = fminf(ax, ay);
    const float z = mn * __builtin_amdgcn_rcpf(fmaxf(mx, 1e-37f));
    float a = atan_poly01(z);
    if (ay > ax) a = 1.5707964f - a;
    if (x < 0.0f) a = 3.1415927f - a;
    return copysignf(a, y);
}

__device__ __forceinline__ float asin_core(float x) {  // asin(x), x in [0,0.5]
    const float x2 = x * x;
    float r = fmaf(x2, 0.03038196f, 0.04464286f);
    r = fmaf(x2, r, 0.075f);
    r = fmaf(x2, r, 0.16666667f);
    return fmaf(x * x2, r, x);
}

__device__ __forceinline__ float asin_fast(float q) {  // q in [-1,1]
    const float a = fabsf(q);
    const float r1 = asin_core(a);
    const float s = sqrtf(fmaxf(0.5f * (1.0f - a), 0.0f));
    const float r2 = 1.5707964f - 2.0f * asin_core(s);
    const float r = (a > 0.5f) ? r2 : r1;
    return copysignf(r, q);
}

__global__ __launch_bounds__(NT, 4) void pointloss_main(
    const float* __restrict__ v,
    const float* __restrict__ nrm,
    const float* __restrict__ unc,
    const float* __restrict__ nown,
    const float* __restrict__ conf,
    const float* __restrict__ lastn,
    const float* __restrict__ lastv,
    const int*   __restrict__ nowm,
    const int*   __restrict__ lastm,
    float* __restrict__ partials)     // [NB*5]
{
    const int base = blockIdx.x * NT + threadIdx.x;   // < STRIDE

    // per-iteration pixel indices; iter 4 may be out of range -> clamp addr
    int   pp[NI];
    bool  pv[NI];
    #pragma unroll
    for (int j = 0; j < NI; ++j) {
        const int pj = base + j * STRIDE;
        pv[j] = (pj < NPIX);
        pp[j] = pv[j] ? pj : base;      // base always in-bounds
    }

    // ---- stage 1: issue ALL streaming loads (45 loads in flight) ----
    float vx[NI], vy[NI], vz[NI], ax[NI], ay[NI], az[NI], cf[NI], uv[NI];
    int mi[NI];
    #pragma unroll
    for (int j = 0; j < NI; ++j) {
        const int p = pp[j];
        vx[j] = v[3*p];    vy[j] = v[3*p+1];    vz[j] = v[3*p+2];
        ax[j] = nown[3*p]; ay[j] = nown[3*p+1]; az[j] = nown[3*p+2];
        mi[j] = nowm[p];   cf[j] = conf[p];     uv[j] = unc[p];
    }

    // ---- stage 2: transcendental block (5 independent chains) ----
    float px[NI], py[NI];
    bool  m0[NI], pred[NI];
    int   gi[NI];
    #pragma unroll
    for (int j = 0; j < NI; ++j) {
        m0[j] = pv[j] && (mi[j] > 0) &&
                ((fabsf(ax[j]) + fabsf(ay[j]) + fabsf(az[j])) != 0.0f);
        const float d2 = vx[j]*vx[j] + vy[j]*vy[j] + vz[j]*vz[j] + EPSF;
        const float q  = fminf(fmaxf(vz[j] * __builtin_amdgcn_rsqf(d2), -1.f), 1.f);
        const float yaw   = atan2_fast(vy[j], vx[j]) * RAD2DEG;
        const float pitch = asin_fast(q) * RAD2DEG;
        px[j] = (180.0f - yaw) * 2.0f;
        py[j] = (3.0f - pitch) * 2.0f;
        const float prx = rintf(px[j]), pry = rintf(py[j]);  // half-even
        const bool inb = (prx >= 0.f) && (prx < 720.f) &&
                         (pry >= 0.f) && (pry < 52.f);
        pred[j] = m0[j] && inb && (cf[j] >= 0.5f);
        gi[j] = pred[j] ? ((pp[j] / HW_) * HW_ + (int)pry * W_ + (int)prx)
                        : pp[j];
    }

    // ---- stage 3: issue ALL gather loads together ----
    float lx[NI], ly[NI], lz[NI], wx[NI], wy[NI], wz[NI];
    float nx[NI], ny[NI], nz[NI];
    int   lmv[NI];
    #pragma unroll
    for (int j = 0; j < NI; ++j) {
        if (pred[j]) {
            const int g = gi[j], p = pp[j];
            lx[j] = lastn[3*g]; ly[j] = lastn[3*g+1]; lz[j] = lastn[3*g+2];
            lmv[j] = lastm[g];
            wx[j] = lastv[3*g]; wy[j] = lastv[3*g+1]; wz[j] = lastv[3*g+2];
            nx[j] = nrm[3*p];   ny[j] = nrm[3*p+1];   nz[j] = nrm[3*p+2];
        }
    }

    // ---- stage 2b: fov accumulation (VALU work covering gather latency) ----
    float s_m0 = 0.f, s_fov = 0.f, s_m = 0.f, s_icp = 0.f, s_ang = 0.f;
    #pragma unroll
    for (int j = 0; j < NI; ++j) {
        if (m0[j]) {
            const float dx = px[j] - fminf(fmaxf(px[j], 0.f), 719.0f);
            const float dy = py[j] - fminf(fmaxf(py[j], 0.f), 51.0f);
            s_m0 += 1.0f;
            s_fov += dx*dx + dy*dy;
        }
    }

    // ---- stage 4: consume gathers ----
    #pragma unroll
    for (int j = 0; j < NI; ++j) {
        if (pred[j] && (lmv[j] > 0) &&
            ((fabsf(lx[j]) + fabsf(ly[j]) + fabsf(lz[j])) != 0.f)) {
            const float r  = lx[j]*(vx[j]-wx[j]) + ly[j]*(vy[j]-wy[j])
                           + lz[j]*(vz[j]-wz[j]);
            const float dt = lx[j]*nx[j] + ly[j]*ny[j] + lz[j]*nz[j];
            const float den = (lx[j]*lx[j] + ly[j]*ly[j] + lz[j]*lz[j]) *
                              (nx[j]*nx[j] + ny[j]*ny[j] + nz[j]*nz[j]) + EPSF;
            const float cosang = fabsf(dt) * __builtin_amdgcn_rsqf(den);
            s_m   += 1.0f;
            s_icp += uv[j] * fabsf(r);
            s_ang += uv[j] * (1.0f - cosang);
        }
    }

    // ---- reduction ----
    #pragma unroll
    for (int off = 32; off > 0; off >>= 1) {
        s_m0  += __shfl_down(s_m0,  off);
        s_fov += __shfl_down(s_fov, off);
        s_m   += __shfl_down(s_m,   off);
        s_icp += __shfl_down(s_icp, off);
        s_ang += __shfl_down(s_ang, off);
    }
    __shared__ float red[NT / 64][5];
    const int lane = threadIdx.x & 63;
    const int wv   = threadIdx.x >> 6;
    if (lane == 0) {
        red[wv][0] = s_m0;  red[wv][1] = s_fov; red[wv][2] = s_m;
        red[wv][3] = s_icp; red[wv][4] = s_ang;
    }
    __syncthreads();
    if (threadIdx.x == 0) {
        float tt[5] = {0.f, 0.f, 0.f, 0.f, 0.f};
        for (int w2 = 0; w2 < NT / 64; ++w2)
            for (int c = 0; c < 5; ++c) tt[c] += red[w2][c];
        float* o = partials + blockIdx.x * 5;
        for (int c = 0; c < 5; ++c) o[c] = tt[c];
    }
}

__global__ __launch_bounds__(256) void pointloss_finalize(
    const float* __restrict__ partials,
    const float* __restrict__ sx,
    const float* __restrict__ sq,
    float* __restrict__ out)
{
    double a0 = 0, a1 = 0, a2 = 0, a3 = 0, a4 = 0;
    for (int i = threadIdx.x; i < NB; i += 256) {
        const float* pq = partials + i * 5;
        a0 += (double)pq[0]; a1 += (double)pq[1]; a2 += (double)pq[2];
        a3 += (double)pq[3]; a4 += (double)pq[4];
    }
    #pragma unroll
    for (int off = 32; off > 0; off >>= 1) {
        a0 += __shfl_down(a0, off);
        a1 += __shfl_down(a1, off);
        a2 += __shfl_down(a2, off);
        a3 += __shfl_down(a3, off);
        a4 += __shfl_down(a4, off);
    }
    __shared__ double red[4][5];
    const int lane = threadIdx.x & 63;
    const int wv   = threadIdx.x >> 6;
    if (lane == 0) {
        red[wv][0] = a0; red[wv][1] = a1; red[wv][2] = a2;
        red[wv][3] = a3; red[wv][4] = a4;
    }
    __syncthreads();
    if (threadIdx.x == 0) {
        double t[5] = {0, 0, 0, 0, 0};
        for (int w2 = 0; w2 < 4; ++w2)
            for (int c = 0; c < 5; ++c) t[c] += red[w2][c];
        const double n0 = fmax(t[0], 1.0);
        const double n  = fmax(t[2], 1.0);
        const double sx0 = (double)sx[0], sq0 = (double)sq[0];
        const double total = exp(-sx0) * (t[3] / n) + sx0
                           + exp(-sq0) * (t[4] / n) + sq0
                           + t[1] / n0;   // LAMDA = 1, ANGRATE = 1
        out[0] = (float)total;
    }
}

extern "C" void kernel_launch(void* const* d_in, const int* in_sizes, int n_in,
                              void* d_out, int out_size, void* d_ws, size_t ws_size,
                              hipStream_t stream) {
    const float* v     = (const float*)d_in[0];
    const float* nrm   = (const float*)d_in[1];
    const float* unc   = (const float*)d_in[2];
    const float* nown  = (const float*)d_in[3];
    const float* conf  = (const float*)d_in[4];
    const float* lastn = (const float*)d_in[5];
    const float* lastv = (const float*)d_in[6];
    const float* sx    = (const float*)d_in[7];
    const float* sq    = (const float*)d_in[8];
    const int*   nowm  = (const int*)d_in[9];
    const int*   lastm = (const int*)d_in[10];

    float* partials = (float*)d_ws;  // NB*5 floats = 40 KB

    pointloss_main<<<NB, NT, 0, stream>>>(
        v, nrm, unc, nown, conf, lastn, lastv, nowm, lastm, partials);
    pointloss_finalize<<<1, 256, 0, stream>>>(partials, sx, sq, (float*)d_out);
}